// Round 14
// baseline (223.205 us; speedup 1.0000x reference)
//
#include <hip/hip_runtime.h>
#include <hip/hip_bf16.h>

#define T_DIM 2048
#define B_DIM 32
#define CIN   80
#define H_DIM 256
#define TT    64               // t-tile per conv block
#define NTB   (T_DIM / TT)     // 32
#define NBLK  (B_DIM * NTB)    // 1024 conv blocks
#define KTOT  (CIN * 3)        // 240
#define KPAD  256              // padded K for bf16 MFMA (k = dk*80+ci ordering)

// LIF chunking (warm-up resync; 0.5^48 ~ 3.5e-15 => exact; verified absmax=0 across sessions)
#define CHUNKS 16
#define CLEN  (T_DIM / CHUNKS) // 128
#define WARM  48
#define SEG   8

// repair chunking
#define RCLEN 64
#define RCH   (T_DIM / RCLEN)  // 32
#define RNT   (RCLEN + WARM)   // 112 LIF steps per repair chunk (= 16 x 7)
#define RNH   16               // flagged h's per pass
#define VSTR  (RNT + 1)        // 113, conflict-free vs stride

#define NPART 64
#define JPER  (NBLK / NPART)   // 16

// Margin threshold: chains with any |v-VTH| < DELTA get full-f64 recompute.
// MFMA 3-split path error sigma ~3e-7; DELTA = 5e-6 = 17 sigma. Validated
// absmax=0 at R17 (5e-5) and R19-R25 (5e-6).
#define DELTA 5e-6

// xp LDS planes for conv MFMA: rows 0..65 = x[t0-1 .. t0+64], rows 66/67 = zero pad
#define XPR 68
#define XPC 88                 // 80 used; 88 => 176B row stride, 16B-aligned frags

// swizzled-B plane stride (elements): 16 ht x 8 ks x 64 lanes x 8 = 65536
#define BSWZ_PL 65536

typedef unsigned short u16;
typedef __attribute__((ext_vector_type(8))) __bf16 bf16x8;
typedef __attribute__((ext_vector_type(2))) __bf16 bf16x2;
typedef __attribute__((ext_vector_type(4))) float f32x4;

// ---- workspace byte offsets ----
// flag[0]=isbf, flag[1]=bf16-mfma probe ok
#define PS_OFF  ((size_t)64)
#define PQ_OFF  (PS_OFF + (size_t)NBLK * H_DIM * 8)
#define PAR_OFF (PQ_OFF + (size_t)NBLK * H_DIM * 8)
#define WT_OFF  (PAR_OFF + (size_t)768 * 8)
#define WTF_OFF (WT_OFF + (size_t)H_DIM * KTOT * 8)
#define PA_OFF  (WTF_OFF + (size_t)H_DIM * KTOT * 4)
#define PB_OFF  (PA_OFF + (size_t)NPART * H_DIM * 8)
#define FLG_OFF (PB_OFF + (size_t)NPART * H_DIM * 8)    // 8192 chain flags
#define WTB_OFF (FLG_OFF + (size_t)8192)                // 3 bf16 planes, swizzled
#define WTB_SZ  ((size_t)3 * H_DIM * KPAD * 2)          // 393,216
#define Y_OFF   (WTB_OFF + WTB_SZ)
#define Y_ELEMS ((size_t)T_DIM * B_DIM * H_DIM)         // 16,777,216 (f32)

__device__ __forceinline__ double bf2d(u16 u) {
    union { unsigned int i; float f; } cv;
    cv.i = ((unsigned int)u) << 16;
    return (double)cv.f;
}

__device__ __forceinline__ float bf2f(u16 u) {
    union { unsigned int i; float f; } cv;
    cv.i = ((unsigned int)u) << 16;
    return cv.f;
}

__device__ __forceinline__ double ld_in(const void* p, int i, int isbf) {
    if (isbf) return bf2d(((const u16*)p)[i]);
    return (double)((const float*)p)[i];
}

__device__ __forceinline__ float ldf(const void* p, int i, int isbf) {
    if (isbf) return bf2f(((const u16*)p)[i]);
    return ((const float*)p)[i];
}

// ---- kernel 0: dtype detect + weight transposes + bf16 MFMA layout probe.
//      block = r (0..239), tid = h — wt/wtf stores fully coalesced; kk/ks/jj
//      wave-uniform. Probe block (240) also zeroes FLG + WTB pad (no memset).
//      WTB swizzle: element = (((p*16+ht)*8+ks)*64 + lane)*8 + j. ----
__global__ __launch_bounds__(256) void k_prep(const u16* __restrict__ xu,
                                              const void* __restrict__ w,
                                              int* __restrict__ flag,
                                              double* __restrict__ wt,
                                              float* __restrict__ wtf,
                                              __bf16* __restrict__ wtb,
                                              unsigned char* __restrict__ flg) {
    __shared__ int cnt[256];
    __shared__ int isbf_s;
    const int tid = threadIdx.x;
    int c = 0;
    for (int j = 0; j < 8; j++) {
        u16 u = xu[tid * 8 + j];
        int e = (u >> 7) & 0xFF;
        if ((u & 0x7FFF) == 0 || (e >= 97 && e <= 157)) c++;
    }
    cnt[tid] = c;
    __syncthreads();
    for (int off = 128; off > 0; off >>= 1) {
        if (tid < off) cnt[tid] += cnt[tid + off];
        __syncthreads();
    }
    if (tid == 0) isbf_s = (cnt[0] >= 1639) ? 1 : 0;
    __syncthreads();
    const int isbf = isbf_s;

    if (blockIdx.x < 240) {
        const int r = blockIdx.x;                // r = ci*3 + dk (uniform)
        const int h = tid;
        const int ci = r / 3;
        const int dk = r - 3 * ci;
        double v = ld_in(w, h * KTOT + r, isbf);
        wt[(size_t)r * H_DIM + h] = v;           // coalesced
        wtf[(size_t)r * H_DIM + h] = (float)v;   // coalesced
        // 3-split bf16, k-order = dk*80+ci, stored fragment-swizzled
        float vf = (float)v;
        __bf16 h1 = (__bf16)vf; float r1 = vf - (float)h1;
        __bf16 h2 = (__bf16)r1; float r2 = r1 - (float)h2;
        __bf16 h3 = (__bf16)r2;
        const int kk = dk * 80 + ci;             // uniform
        const int ks = kk >> 5, t5 = kk & 31;    // uniform
        const int hi2 = t5 >> 3, jj = t5 & 7;    // uniform
        const int ht = h >> 4, rw = h & 15;
        const size_t base = (((size_t)ht * 8 + ks) * 64 + (hi2 * 16 + rw)) * 8 + jj;
        wtb[base] = h1;
        wtb[base + BSWZ_PL] = h2;
        wtb[base + 2 * BSWZ_PL] = h3;
    } else {
        // probe mfma_f32_16x16x32_bf16 layout (asymmetric ints, exact in bf16/f32)
        if (tid < 64) {
            const int l = tid, row = l & 15, hi = l >> 4;
            bf16x8 af, bff;
#pragma unroll
            for (int j = 0; j < 8; j++) {
                int k = hi * 8 + j;
                af[j]  = (__bf16)(float)((row * 5 + k * 3) % 7 - 3);
                bff[j] = (__bf16)(float)((k * 11 + row * 2) % 5 - 2);
            }
            f32x4 cc;
#pragma unroll
            for (int r = 0; r < 4; r++) cc[r] = (float)((4 * hi + r) * 100 + row);
            f32x4 d = __builtin_amdgcn_mfma_f32_16x16x32_bf16(af, bff, cc, 0, 0, 0);
            bool ok = true;
#pragma unroll
            for (int r = 0; r < 4; r++) {
                float ref = (float)((4 * hi + r) * 100 + row);
                for (int k = 0; k < 32; k++)
                    ref += (float)(((4 * hi + r) * 5 + k * 3) % 7 - 3) *
                           (float)((k * 11 + row * 2) % 5 - 2);
                if (d[r] != ref) ok = false;
            }
            ok = __all(ok);
            if (l == 0) flag[1] = ok ? 1 : 0;
        }
        if (tid == 0) flag[0] = isbf;
        // zero FLG every iteration (graph replay; replaces hipMemsetAsync)
        for (int i = tid; i < 8192; i += 256) flg[i] = 0;
        // zero WTB pad = exact unwritten set: ks=7, lanes 32..63, per ht, per plane
        for (int i = tid; i < 3 * 16 * 256; i += 256) {
            int p   = i >> 12;
            int rem = i & 4095;
            int ht  = rem >> 8;
            int e   = rem & 255;
            wtb[(size_t)p * BSWZ_PL + ht * 4096 + 3840 + e] = (__bf16)0.0f;
        }
    }
}

// ---- kernel 1: conv1d as bf16 3-split MFMA GEMM (6 products, validated R17).
//      R26: __launch_bounds__(256,3) — 3 blocks/CU, reg cap floor(512/3)=170
//      >= the ~160 unified (96 VGPR + 64 AGPR) this kernel needs, LDS 3x36KB
//      = 109KB <= 160KB. R22's (256,4) capped at 128 and spilled — (256,3) is
//      the rung between. SPILL SENTINEL: FETCH must stay ~13.8 MB. ----
__global__ __launch_bounds__(256, 3) void k_convb(const void* __restrict__ x,
                                                  const void* __restrict__ bias,
                                                  const int* __restrict__ flag,
                                                  const __bf16* __restrict__ wtb,
                                                  float* __restrict__ y,
                                                  double* __restrict__ ps,
                                                  double* __restrict__ pq) {
    if (flag[1] != 1) return;
    __shared__ __bf16 xp[3][XPR][XPC];           // 35.9 KB
    const int isbf = flag[0];
    const int tb = blockIdx.x;
    const int b  = blockIdx.y;
    const int t0 = tb * TT;
    const int tid = threadIdx.x;

    // stage x[t0-1 .. t0+64] -> 3-split bf16 planes, 2 ci per thread-iter
    for (int idx = tid; idx < 66 * (CIN / 2); idx += 256) {
        int tl = idx / (CIN / 2);
        int cp = idx - tl * (CIN / 2);
        int ci = cp * 2;
        int tg = t0 - 1 + tl;
        float v0 = 0.0f, v1 = 0.0f;
        if (tg >= 0 && tg < T_DIM) {
            const size_t base = (size_t)(b * T_DIM + tg) * CIN + ci;
            if (isbf) {
                unsigned int u = *(const unsigned int*)((const u16*)x + base);
                v0 = bf2f((u16)u); v1 = bf2f((u16)(u >> 16));
            } else {
                float2 f = *(const float2*)((const float*)x + base);
                v0 = f.x; v1 = f.y;
            }
        }
        __bf16 a1 = (__bf16)v0; float r1 = v0 - (float)a1;
        __bf16 a2 = (__bf16)r1; float r2 = r1 - (float)a2;
        __bf16 a3 = (__bf16)r2;
        __bf16 c1 = (__bf16)v1; float s1 = v1 - (float)c1;
        __bf16 c2 = (__bf16)s1; float s2 = s1 - (float)c2;
        __bf16 c3 = (__bf16)s2;
        *(bf16x2*)&xp[0][tl][ci] = bf16x2{a1, c1};
        *(bf16x2*)&xp[1][tl][ci] = bf16x2{a2, c2};
        *(bf16x2*)&xp[2][tl][ci] = bf16x2{a3, c3};
    }
    // zero rows 66,67 (k>=240 pad redirect), bf16x2 packed
    for (int idx = tid; idx < 2 * (XPC / 2); idx += 256) {
        int r = 66 + idx / (XPC / 2), cc = (idx % (XPC / 2)) * 2;
        bf16x2 z = {(__bf16)0.0f, (__bf16)0.0f};
        *(bf16x2*)&xp[0][r][cc] = z;
        *(bf16x2*)&xp[1][r][cc] = z;
        *(bf16x2*)&xp[2][r][cc] = z;
    }
    __syncthreads();

    const int wave = tid >> 6;
    const int lane = tid & 63;
    const int row  = lane & 15;
    const int hi   = lane >> 4;
    const int h0w  = wave * 64;
    const int PL   = XPR * XPC;                  // xp plane stride (elements)

    f32x4 acc[4][4];
#pragma unroll
    for (int m = 0; m < 4; m++)
#pragma unroll
        for (int n = 0; n < 4; n++)
#pragma unroll
            for (int r = 0; r < 4; r++) acc[m][n][r] = 0.0f;

    // swizzled B base for (ks, nf): wtb + ((wave*4+nf)*8 + ks)*512 + lane*8
    const __bf16* bw = wtb + ((size_t)wave * 4 * 8) * 512 + (size_t)lane * 8;

    // B prefetch: group g (0..31): ks=g>>2, nf=g&3, slot=g&3. 4-deep rotation.
    bf16x8 bb[4][3];
#pragma unroll
    for (int g = 0; g < 4; g++) {
        const __bf16* bp = bw + ((size_t)(g & 3) * 8 + 0) * 512;   // ks=0
        bb[g][0] = *(const bf16x8*)bp;
        bb[g][1] = *(const bf16x8*)(bp + BSWZ_PL);
        bb[g][2] = *(const bf16x8*)(bp + 2 * BSWZ_PL);
    }

    bf16x8 a[2][4][3];                            // double-buffered A
    {   // A for ks=0
        const int kb0 = hi * 8;
        const int dk = (kb0 >= 160) ? 2 : ((kb0 >= 80) ? 1 : 0);
        const int ci0 = kb0 - dk * 80;
#pragma unroll
        for (int m = 0; m < 4; m++) {
            const __bf16* ap = &xp[0][row + m * 16 + dk][ci0];
            a[0][m][0] = *(const bf16x8*)ap;
            a[0][m][1] = *(const bf16x8*)(ap + PL);
            a[0][m][2] = *(const bf16x8*)(ap + 2 * PL);
        }
    }

#pragma unroll
    for (int g = 0; g < 32; g++) {
        const int ks = g >> 2, nf = g & 3, slot = g & 3, ab = ks & 1;

#pragma unroll
        for (int m = 0; m < 4; m++) {
            acc[m][nf] = __builtin_amdgcn_mfma_f32_16x16x32_bf16(a[ab][m][0], bb[slot][0], acc[m][nf], 0, 0, 0);
            acc[m][nf] = __builtin_amdgcn_mfma_f32_16x16x32_bf16(a[ab][m][0], bb[slot][1], acc[m][nf], 0, 0, 0);
            acc[m][nf] = __builtin_amdgcn_mfma_f32_16x16x32_bf16(a[ab][m][1], bb[slot][0], acc[m][nf], 0, 0, 0);
            acc[m][nf] = __builtin_amdgcn_mfma_f32_16x16x32_bf16(a[ab][m][0], bb[slot][2], acc[m][nf], 0, 0, 0);
            acc[m][nf] = __builtin_amdgcn_mfma_f32_16x16x32_bf16(a[ab][m][1], bb[slot][1], acc[m][nf], 0, 0, 0);
            acc[m][nf] = __builtin_amdgcn_mfma_f32_16x16x32_bf16(a[ab][m][2], bb[slot][0], acc[m][nf], 0, 0, 0);
        }

        // A prefetch for ks+1 at nf==2
        if (nf == 2 && ks + 1 < 8) {
            const int kb0 = (ks + 1) * 32 + hi * 8;
            const int dk = (kb0 >= 160) ? 2 : ((kb0 >= 80) ? 1 : 0);
            const int ci0 = kb0 - dk * 80;
            const bool pad = (kb0 >= KTOT);
#pragma unroll
            for (int m = 0; m < 4; m++) {
                const __bf16* ap = pad ? &xp[0][66][0] : &xp[0][row + m * 16 + dk][ci0];
                a[ab ^ 1][m][0] = *(const bf16x8*)ap;
                a[ab ^ 1][m][1] = *(const bf16x8*)(ap + PL);
                a[ab ^ 1][m][2] = *(const bf16x8*)(ap + 2 * PL);
            }
        }

        // B prefetch for group g+4 into the slot just consumed (coalesced 1 KB)
        if (g + 4 < 32) {
            const int g4 = g + 4;
            const __bf16* bp = bw + ((size_t)(g4 & 3) * 8 + (g4 >> 2)) * 512;
            bb[slot][0] = *(const bf16x8*)bp;
            bb[slot][1] = *(const bf16x8*)(bp + BSWZ_PL);
            bb[slot][2] = *(const bf16x8*)(bp + 2 * BSWZ_PL);
        }
    }

    // epilogue: bias + y stores + fused BN partials (C: col=row, row=4*hi+r)
    const int blk = b * NTB + tb;
#pragma unroll
    for (int nf = 0; nf < 4; nf++) {
        const int h_out = h0w + nf * 16 + row;
        const double bv = ld_in(bias, h_out, isbf);
        double s1 = 0.0, s2 = 0.0;
#pragma unroll
        for (int m = 0; m < 4; m++)
#pragma unroll
            for (int r = 0; r < 4; r++) {
                double v = (double)acc[m][nf][r] + bv;
                y[((size_t)(t0 + m * 16 + 4 * hi + r) * B_DIM + b) * H_DIM + h_out] = (float)v;
                s1 += v;
                s2 = fma(v, v, s2);
            }
        s1 += __shfl_xor(s1, 16); s1 += __shfl_xor(s1, 32);
        s2 += __shfl_xor(s2, 16); s2 += __shfl_xor(s2, 32);
        if (hi == 0) {
            ps[(size_t)blk * H_DIM + h0w + nf * 16 + row] = s1;
            pq[(size_t)blk * H_DIM + h0w + nf * 16 + row] = s2;
        }
    }
}

// ---- kernel 1F: f32 VALU conv fallback (runs only if probe failed) ----
__global__ __launch_bounds__(256, 8) void k_convf(const void* __restrict__ x,
                                                  const void* __restrict__ bias,
                                                  const int* __restrict__ flag,
                                                  const float* __restrict__ wtf,
                                                  float* __restrict__ y,
                                                  double* __restrict__ ps,
                                                  double* __restrict__ pq) {
    if (flag[1] == 1) return;
    __shared__ __align__(16) float xs[CIN * (TT + 2)];
    const int isbf = flag[0];
    const int tb = blockIdx.x;
    const int b  = blockIdx.y;
    const int t0 = tb * TT;

    for (int idx = threadIdx.x; idx < CIN * (TT + 2); idx += 256) {
        int tl = idx / CIN;
        int ci = idx - tl * CIN;
        int tg = t0 - 1 + tl;
        float v = 0.0f;
        if (tg >= 0 && tg < T_DIM) v = ldf(x, (b * T_DIM + tg) * CIN + ci, isbf);
        xs[ci * (TT + 2) + tl] = v;
    }
    __syncthreads();

    const int h = threadIdx.x;
    float acc[TT];
    const float bv = ldf(bias, h, isbf);
#pragma unroll
    for (int i = 0; i < TT; i++) acc[i] = bv;

    const float* wp = wtf + h;
    float w0 = wp[0], w1 = wp[H_DIM], w2 = wp[2 * H_DIM];
    for (int ci = 0; ci < CIN; ci++) {
        float wn0 = 0.0f, wn1 = 0.0f, wn2 = 0.0f;
        if (ci + 1 < CIN) {
            const float* wq = wtf + (size_t)(ci + 1) * 3 * H_DIM + h;
            wn0 = wq[0]; wn1 = wq[H_DIM]; wn2 = wq[2 * H_DIM];
        }
        const float* xr = xs + ci * (TT + 2);
        float x0 = xr[0], x1 = xr[1];
#pragma unroll
        for (int tt = 0; tt < TT; tt += 2) {
            float2 xp2 = *(const float2*)(xr + tt + 2);
            acc[tt]     = fmaf(w2, xp2.x, fmaf(w1, x1,    fmaf(w0, x0, acc[tt])));
            acc[tt + 1] = fmaf(w2, xp2.y, fmaf(w1, xp2.x, fmaf(w0, x1, acc[tt + 1])));
            x0 = xp2.x; x1 = xp2.y;
        }
        w0 = wn0; w1 = wn1; w2 = wn2;
    }

    const int blk = b * NTB + tb;
    double s1 = 0.0, s2 = 0.0;
#pragma unroll
    for (int tt = 0; tt < TT; tt++) {
        y[((size_t)(t0 + tt) * B_DIM + b) * H_DIM + h] = acc[tt];
        double a = (double)acc[tt];
        s1 += a;
        s2 = fma(a, a, s2);
    }
    ps[(size_t)blk * H_DIM + h] = s1;
    pq[(size_t)blk * H_DIM + h] = s2;
}

// ---- kernel 2a: partial BN reduce ----
__global__ __launch_bounds__(256) void k_statsA(const double* __restrict__ ps,
                                                const double* __restrict__ pq,
                                                double* __restrict__ pa,
                                                double* __restrict__ pb) {
    const int h = threadIdx.x;
    const int k = blockIdx.x;
    double s1 = 0.0, s2 = 0.0;
    const int j0 = k * JPER;
    for (int j = j0; j < j0 + JPER; j++) {
        s1 += ps[(size_t)j * H_DIM + h];
        s2 += pq[(size_t)j * H_DIM + h];
    }
    pa[(size_t)k * H_DIM + h] = s1;
    pb[(size_t)k * H_DIM + h] = s2;
}

// ---- kernel 2b: final reduce + fold BN affine (once, in 1 block — R24 lesson) ----
__global__ __launch_bounds__(256) void k_statsB(const double* __restrict__ pa,
                                                const double* __restrict__ pb,
                                                const void* __restrict__ gamma,
                                                const void* __restrict__ beta,
                                                const int* __restrict__ flag,
                                                double* __restrict__ par) {
    const int isbf = flag[0];
    const int h = threadIdx.x;
    double s1 = 0.0, s2 = 0.0;
    for (int k = 0; k < NPART; k++) {
        s1 += pa[(size_t)k * H_DIM + h];
        s2 += pb[(size_t)k * H_DIM + h];
    }
    const double N = (double)T_DIM * (double)B_DIM;
    double mean = s1 / N;
    double var  = s2 / N - mean * mean;
    double r    = 1.0 / sqrt(var + 1e-5);
    par[h]       = mean;
    par[256 + h] = r * ld_in(gamma, h, isbf);
    par[512 + h] = ld_in(beta, h, isbf);
}

// ---- kernel 3: chunked LIF from f32 Y (no LDS, register double-buffer,
//      barrier-free). Flags margin-critical chains for f64 repair. ----
__global__ __launch_bounds__(256) void k_lif(const float* __restrict__ y,
                                             const double* __restrict__ par,
                                             const int* __restrict__ flag,
                                             unsigned char* __restrict__ flg,
                                             void* __restrict__ out) {
    const int isbf = flag[0];
    const int c = blockIdx.x, b = blockIdx.y, h = threadIdx.x;
    const int t_out = c * CLEN;
    int t_begin = t_out - WARM; if (t_begin < 0) t_begin = 0;
    const int nseg = (t_out + CLEN - t_begin) / SEG;   // 16 (c=0) or 22 — always even

    const double m  = par[h];
    const double A  = par[256 + h];
    const double be = par[512 + h];

    const size_t ST = (size_t)B_DIM * H_DIM;
    const float* yb = y + (size_t)b * H_DIM + h;
    u16*   ob16 = (u16*)out + (size_t)b * H_DIM + h;
    float* ob32 = (float*)out + (size_t)b * H_DIM + h;

    float ga[SEG], gb[SEG];
#pragma unroll
    for (int k = 0; k < SEG; k++) ga[k] = yb[(size_t)(t_begin + k) * ST];

    double v = 0.0;
    bool anyf = false;

#define LIF_SEG(GR, TBASE)                                                    \
    {                                                                         \
        const int t0s = (TBASE);                                              \
        _Pragma("unroll")                                                     \
        for (int k = 0; k < SEG; k++) {                                       \
            double val = fma((double)GR[k] - m, A, be);                       \
            v = fma(v, 0.5, val);                                             \
            double mg = v - 1.0;                                              \
            bool sp = mg >= 0.0;                                              \
            anyf |= (fabs(mg) < DELTA);                                       \
            const int t = t0s + k;                                            \
            if (t >= t_out) {                                                 \
                size_t oi = (size_t)t * ST;                                   \
                if (isbf) ob16[oi] = sp ? (u16)0x3F80 : (u16)0;               \
                else      ob32[oi] = sp ? 1.0f : 0.0f;                        \
            }                                                                 \
            v = sp ? 0.0 : v;                                                 \
        }                                                                     \
    }

    for (int s = 0; s < nseg; s += 2) {
        const int t1 = t_begin + (s + 1) * SEG;
        if (s + 1 < nseg) {
#pragma unroll
            for (int k = 0; k < SEG; k++) gb[k] = yb[(size_t)(t1 + k) * ST];
        }
        LIF_SEG(ga, t_begin + s * SEG);
        const int t2 = t_begin + (s + 2) * SEG;
        if (s + 2 < nseg) {
#pragma unroll
            for (int k = 0; k < SEG; k++) ga[k] = yb[(size_t)(t2 + k) * ST];
        }
        if (s + 1 < nseg) LIF_SEG(gb, t1);
    }
#undef LIF_SEG

    if (anyf) flg[(b << 8) | h] = 1;
}

// ---- kernel 4: tiled f64 repair (validated R19). Grid (RCH, B); early-exit
//      if no flagged h; x staged once coalesced; thread ti computes t in
//      [7ti,7ti+7); per-h chunked LIF with WARM=48 resync (t<0 -> vs=0). ----
__global__ __launch_bounds__(256) void k_repair(const void* __restrict__ x,
                                                const void* __restrict__ bias,
                                                const double* __restrict__ wt,
                                                const double* __restrict__ par,
                                                const int* __restrict__ flag,
                                                const unsigned char* __restrict__ flg,
                                                void* __restrict__ out) {
    __shared__ int nf_s;
    __shared__ u16 hl[256];
    __shared__ float xs[CIN * (RNT + 2)];    // 36.5 KB
    __shared__ double vs[RNH * VSTR];        // 14.5 KB

    const int b = blockIdx.y;
    const int tid = threadIdx.x;

    if (tid == 0) nf_s = 0;
    __syncthreads();
    if (flg[(b << 8) | tid]) { int p = atomicAdd(&nf_s, 1); hl[p] = (u16)tid; }
    __syncthreads();
    const int nf = nf_s;
    if (nf == 0) return;

    const int isbf = flag[0];
    const int t_out = blockIdx.x * RCLEN;
    const int t_begin = t_out - WARM;

    for (int idx = tid; idx < CIN * (RNT + 2); idx += 256) {
        int tl = idx / CIN;
        int ci = idx - tl * CIN;
        int tg = t_begin - 1 + tl;
        float v = 0.0f;
        if (tg >= 0 && tg < T_DIM) v = ldf(x, (b * T_DIM + tg) * CIN + ci, isbf);
        xs[ci * (RNT + 2) + tl] = v;
    }

    const int hi = tid >> 4;                 // wave-aligned h-groups
    const int ti = tid & 15;                 // covers t = 7*ti .. 7*ti+6

    for (int g0 = 0; g0 < nf; g0 += RNH) {
        const int h = (g0 + hi < nf) ? (int)hl[g0 + hi] : -1;
        __syncthreads();

        if (h >= 0) {
            const double bv = ld_in(bias, h, isbf);
            const double m  = par[h];
            const double A  = par[256 + h];
            const double be = par[512 + h];
            double acc[7];
#pragma unroll
            for (int k = 0; k < 7; k++) acc[k] = bv;
            const double* wq = wt + h;
            for (int ci = 0; ci < CIN; ci++) {
                const double w0 = wq[0], w1 = wq[H_DIM], w2 = wq[2 * H_DIM];
                wq += 3 * H_DIM;
                const float* xr = xs + ci * (RNT + 2) + ti * 7;
                float xv[9];
#pragma unroll
                for (int j = 0; j < 9; j++) xv[j] = xr[j];
#pragma unroll
                for (int k = 0; k < 7; k++)
                    acc[k] = fma(w0, (double)xv[k],
                             fma(w1, (double)xv[k + 1],
                             fma(w2, (double)xv[k + 2], acc[k])));
            }
#pragma unroll
            for (int k = 0; k < 7; k++) {
                const int tt = ti * 7 + k;
                vs[hi * VSTR + tt] = (t_begin + tt < 0) ? 0.0 : fma(acc[k] - m, A, be);
            }
        }
        __syncthreads();

        if (tid < RNH && g0 + tid < nf) {
            const int h2 = (int)hl[g0 + tid];
            const double* vr = vs + tid * VSTR;
            double v = 0.0;
            for (int tt = 0; tt < RNT; tt++) {
                v = fma(v, 0.5, vr[tt]);
                bool sp = (v - 1.0) >= 0.0;
                const int t = t_begin + tt;
                if (t >= t_out) {
                    size_t oi = ((size_t)t * B_DIM + b) * H_DIM + h2;
                    if (isbf) ((u16*)out)[oi] = sp ? (u16)0x3F80 : (u16)0;
                    else      ((float*)out)[oi] = sp ? 1.0f : 0.0f;
                }
                v = sp ? 0.0 : v;
            }
        }
    }
}

// ---- diagnostic: ws too small ----
__global__ void k_code(u16* out, float code) {
    if (threadIdx.x == 0 && blockIdx.x == 0) {
        union { unsigned int i; float f; } cv; cv.f = code;
        out[0] = (u16)(cv.i >> 16);
    }
}

extern "C" void kernel_launch(void* const* d_in, const int* in_sizes, int n_in,
                              void* d_out, int out_size, void* d_ws, size_t ws_size,
                              hipStream_t stream) {
    const void* x     = d_in[0];
    const void* w     = d_in[1];
    const void* cb    = d_in[2];
    const void* gamma = d_in[3];
    const void* beta  = d_in[4];

    char* wsb   = (char*)d_ws;
    int* flag   = (int*)wsb;
    double* PS  = (double*)(wsb + PS_OFF);
    double* PQ  = (double*)(wsb + PQ_OFF);
    double* PAR = (double*)(wsb + PAR_OFF);
    double* WT  = (double*)(wsb + WT_OFF);
    float*  WTF = (float*)(wsb + WTF_OFF);
    double* PA  = (double*)(wsb + PA_OFF);
    double* PB  = (double*)(wsb + PB_OFF);
    unsigned char* FLG = (unsigned char*)(wsb + FLG_OFF);
    __bf16* WTB = (__bf16*)(wsb + WTB_OFF);
    float* Yp   = (float*)(wsb + Y_OFF);

    const size_t need = Y_OFF + Y_ELEMS * 4;

    if (ws_size < need) {
        hipMemsetAsync(d_out, 0, (size_t)out_size * 2, stream);
        k_code<<<1, 64, 0, stream>>>((u16*)d_out, 1000.0f);
        return;
    }

    k_prep<<<dim3(241), dim3(256), 0, stream>>>((const u16*)x, w, flag, WT, WTF, WTB, FLG);
    k_convb<<<dim3(NTB, B_DIM), dim3(256), 0, stream>>>(
        x, cb, flag, WTB, Yp, PS, PQ);
    k_convf<<<dim3(NTB, B_DIM), dim3(256), 0, stream>>>(
        x, cb, flag, WTF, Yp, PS, PQ);
    k_statsA<<<dim3(NPART), dim3(256), 0, stream>>>(PS, PQ, PA, PB);
    k_statsB<<<dim3(1), dim3(256), 0, stream>>>(PA, PB, gamma, beta, flag, PAR);
    k_lif<<<dim3(CHUNKS, B_DIM), dim3(256), 0, stream>>>(Yp, PAR, flag, FLG, d_out);
    k_repair<<<dim3(RCH, B_DIM), dim3(256), 0, stream>>>(
        x, cb, WT, PAR, flag, FLG, d_out);
}

// Round 15
// 213.008 us; speedup vs baseline: 1.0479x; 1.0479x over previous
//
#include <hip/hip_runtime.h>
#include <hip/hip_bf16.h>

#define T_DIM 2048
#define B_DIM 32
#define CIN   80
#define H_DIM 256
#define TT    64               // t-tile per conv block
#define NTB   (T_DIM / TT)     // 32
#define NBLK  (B_DIM * NTB)    // 1024 conv blocks
#define KTOT  (CIN * 3)        // 240
#define KPAD  256              // padded K for bf16 MFMA (k = dk*80+ci ordering)

// LIF chunking (warm-up resync; 0.5^48 ~ 3.5e-15 => exact; verified absmax=0 across sessions)
#define CHUNKS 16
#define CLEN  (T_DIM / CHUNKS) // 128
#define WARM  48
#define SEG   8

// repair chunking
#define RCLEN 64
#define RCH   (T_DIM / RCLEN)  // 32
#define RNT   (RCLEN + WARM)   // 112 LIF steps per repair chunk (= 16 x 7)
#define RNH   16               // flagged h's per pass
#define VSTR  (RNT + 1)        // 113, conflict-free vs stride

#define NPART 64
#define JPER  (NBLK / NPART)   // 16

// Margin threshold: chains with any |v-VTH| < DELTA get full-f64 recompute.
// MFMA 3-split path error sigma ~3e-7; DELTA = 5e-6 = 17 sigma. Validated
// absmax=0 at R17 (5e-5) and R19-R26 (5e-6).
#define DELTA 5e-6

// xp LDS planes for conv MFMA: rows 0..65 = x[t0-1 .. t0+64], rows 66/67 = zero pad
#define XPR 68
#define XPC 88                 // 80 used; 88 => 176B row stride, 16B-aligned frags

// swizzled-B plane stride (elements): 16 ht x 8 ks x 64 lanes x 8 = 65536
#define BSWZ_PL 65536

typedef unsigned short u16;
typedef __attribute__((ext_vector_type(8))) __bf16 bf16x8;
typedef __attribute__((ext_vector_type(2))) __bf16 bf16x2;
typedef __attribute__((ext_vector_type(4))) float f32x4;

// ---- workspace byte offsets ----
// flag[0]=isbf, flag[1]=bf16-mfma probe ok
#define PS_OFF  ((size_t)64)
#define PQ_OFF  (PS_OFF + (size_t)NBLK * H_DIM * 8)
#define PAR_OFF (PQ_OFF + (size_t)NBLK * H_DIM * 8)
#define WT_OFF  (PAR_OFF + (size_t)768 * 8)
#define WTF_OFF (WT_OFF + (size_t)H_DIM * KTOT * 8)
#define PA_OFF  (WTF_OFF + (size_t)H_DIM * KTOT * 4)
#define PB_OFF  (PA_OFF + (size_t)NPART * H_DIM * 8)
#define FLG_OFF (PB_OFF + (size_t)NPART * H_DIM * 8)    // 8192 chain flags
#define WTB_OFF (FLG_OFF + (size_t)8192)                // 3 bf16 planes, swizzled
#define WTB_SZ  ((size_t)3 * H_DIM * KPAD * 2)          // 393,216
#define Y_OFF   (WTB_OFF + WTB_SZ)
#define Y_ELEMS ((size_t)T_DIM * B_DIM * H_DIM)         // 16,777,216 (f32)

__device__ __forceinline__ double bf2d(u16 u) {
    union { unsigned int i; float f; } cv;
    cv.i = ((unsigned int)u) << 16;
    return (double)cv.f;
}

__device__ __forceinline__ float bf2f(u16 u) {
    union { unsigned int i; float f; } cv;
    cv.i = ((unsigned int)u) << 16;
    return cv.f;
}

__device__ __forceinline__ double ld_in(const void* p, int i, int isbf) {
    if (isbf) return bf2d(((const u16*)p)[i]);
    return (double)((const float*)p)[i];
}

__device__ __forceinline__ float ldf(const void* p, int i, int isbf) {
    if (isbf) return bf2f(((const u16*)p)[i]);
    return ((const float*)p)[i];
}

// ---- kernel 0: dtype detect + weight transposes + bf16 MFMA layout probe.
//      block = r (0..239), tid = h — wt/wtf stores fully coalesced; kk/ks/jj
//      wave-uniform. Probe block (240) also zeroes FLG + WTB pad (no memset).
//      WTB swizzle: element = (((p*16+ht)*8+ks)*64 + lane)*8 + j. ----
__global__ __launch_bounds__(256) void k_prep(const u16* __restrict__ xu,
                                              const void* __restrict__ w,
                                              int* __restrict__ flag,
                                              double* __restrict__ wt,
                                              float* __restrict__ wtf,
                                              __bf16* __restrict__ wtb,
                                              unsigned char* __restrict__ flg) {
    __shared__ int cnt[256];
    __shared__ int isbf_s;
    const int tid = threadIdx.x;
    int c = 0;
    for (int j = 0; j < 8; j++) {
        u16 u = xu[tid * 8 + j];
        int e = (u >> 7) & 0xFF;
        if ((u & 0x7FFF) == 0 || (e >= 97 && e <= 157)) c++;
    }
    cnt[tid] = c;
    __syncthreads();
    for (int off = 128; off > 0; off >>= 1) {
        if (tid < off) cnt[tid] += cnt[tid + off];
        __syncthreads();
    }
    if (tid == 0) isbf_s = (cnt[0] >= 1639) ? 1 : 0;
    __syncthreads();
    const int isbf = isbf_s;

    if (blockIdx.x < 240) {
        const int r = blockIdx.x;                // r = ci*3 + dk (uniform)
        const int h = tid;
        const int ci = r / 3;
        const int dk = r - 3 * ci;
        double v = ld_in(w, h * KTOT + r, isbf);
        wt[(size_t)r * H_DIM + h] = v;           // coalesced
        wtf[(size_t)r * H_DIM + h] = (float)v;   // coalesced
        // 3-split bf16, k-order = dk*80+ci, stored fragment-swizzled
        float vf = (float)v;
        __bf16 h1 = (__bf16)vf; float r1 = vf - (float)h1;
        __bf16 h2 = (__bf16)r1; float r2 = r1 - (float)h2;
        __bf16 h3 = (__bf16)r2;
        const int kk = dk * 80 + ci;             // uniform
        const int ks = kk >> 5, t5 = kk & 31;    // uniform
        const int hi2 = t5 >> 3, jj = t5 & 7;    // uniform
        const int ht = h >> 4, rw = h & 15;
        const size_t base = (((size_t)ht * 8 + ks) * 64 + (hi2 * 16 + rw)) * 8 + jj;
        wtb[base] = h1;
        wtb[base + BSWZ_PL] = h2;
        wtb[base + 2 * BSWZ_PL] = h3;
    } else {
        // probe mfma_f32_16x16x32_bf16 layout (asymmetric ints, exact in bf16/f32)
        if (tid < 64) {
            const int l = tid, row = l & 15, hi = l >> 4;
            bf16x8 af, bff;
#pragma unroll
            for (int j = 0; j < 8; j++) {
                int k = hi * 8 + j;
                af[j]  = (__bf16)(float)((row * 5 + k * 3) % 7 - 3);
                bff[j] = (__bf16)(float)((k * 11 + row * 2) % 5 - 2);
            }
            f32x4 cc;
#pragma unroll
            for (int r = 0; r < 4; r++) cc[r] = (float)((4 * hi + r) * 100 + row);
            f32x4 d = __builtin_amdgcn_mfma_f32_16x16x32_bf16(af, bff, cc, 0, 0, 0);
            bool ok = true;
#pragma unroll
            for (int r = 0; r < 4; r++) {
                float ref = (float)((4 * hi + r) * 100 + row);
                for (int k = 0; k < 32; k++)
                    ref += (float)(((4 * hi + r) * 5 + k * 3) % 7 - 3) *
                           (float)((k * 11 + row * 2) % 5 - 2);
                if (d[r] != ref) ok = false;
            }
            ok = __all(ok);
            if (l == 0) flag[1] = ok ? 1 : 0;
        }
        if (tid == 0) flag[0] = isbf;
        // zero FLG every iteration (graph replay; replaces hipMemsetAsync)
        for (int i = tid; i < 8192; i += 256) flg[i] = 0;
        // zero WTB pad = exact unwritten set: ks=7, lanes 32..63, per ht, per plane
        for (int i = tid; i < 3 * 16 * 256; i += 256) {
            int p   = i >> 12;
            int rem = i & 4095;
            int ht  = rem >> 8;
            int e   = rem & 255;
            wtb[(size_t)p * BSWZ_PL + ht * 4096 + 3840 + e] = (__bf16)0.0f;
        }
    }
}

// ---- kernel 1: conv1d as bf16 3-split MFMA GEMM (6 products, validated R17).
//      TERMINAL CONFIG (256,2): unified VGPR+AGPR ~160/wave needs the full
//      256-reg band. Both higher-occupancy rungs are MEASURED spills:
//      (256,4) R22: FETCH 13.7->132 MB, conv 63->130 us;
//      (256,3) R26: VGPR forced 96->84, FETCH 13.8->21.7 MB, conv ->86 us.
//      Deep-prefetch ILP trades occupancy deliberately — do not touch. ----
__global__ __launch_bounds__(256, 2) void k_convb(const void* __restrict__ x,
                                                  const void* __restrict__ bias,
                                                  const int* __restrict__ flag,
                                                  const __bf16* __restrict__ wtb,
                                                  float* __restrict__ y,
                                                  double* __restrict__ ps,
                                                  double* __restrict__ pq) {
    if (flag[1] != 1) return;
    __shared__ __bf16 xp[3][XPR][XPC];           // 35.9 KB
    const int isbf = flag[0];
    const int tb = blockIdx.x;
    const int b  = blockIdx.y;
    const int t0 = tb * TT;
    const int tid = threadIdx.x;

    // stage x[t0-1 .. t0+64] -> 3-split bf16 planes, 2 ci per thread-iter
    for (int idx = tid; idx < 66 * (CIN / 2); idx += 256) {
        int tl = idx / (CIN / 2);
        int cp = idx - tl * (CIN / 2);
        int ci = cp * 2;
        int tg = t0 - 1 + tl;
        float v0 = 0.0f, v1 = 0.0f;
        if (tg >= 0 && tg < T_DIM) {
            const size_t base = (size_t)(b * T_DIM + tg) * CIN + ci;
            if (isbf) {
                unsigned int u = *(const unsigned int*)((const u16*)x + base);
                v0 = bf2f((u16)u); v1 = bf2f((u16)(u >> 16));
            } else {
                float2 f = *(const float2*)((const float*)x + base);
                v0 = f.x; v1 = f.y;
            }
        }
        __bf16 a1 = (__bf16)v0; float r1 = v0 - (float)a1;
        __bf16 a2 = (__bf16)r1; float r2 = r1 - (float)a2;
        __bf16 a3 = (__bf16)r2;
        __bf16 c1 = (__bf16)v1; float s1 = v1 - (float)c1;
        __bf16 c2 = (__bf16)s1; float s2 = s1 - (float)c2;
        __bf16 c3 = (__bf16)s2;
        *(bf16x2*)&xp[0][tl][ci] = bf16x2{a1, c1};
        *(bf16x2*)&xp[1][tl][ci] = bf16x2{a2, c2};
        *(bf16x2*)&xp[2][tl][ci] = bf16x2{a3, c3};
    }
    // zero rows 66,67 (k>=240 pad redirect), bf16x2 packed
    for (int idx = tid; idx < 2 * (XPC / 2); idx += 256) {
        int r = 66 + idx / (XPC / 2), cc = (idx % (XPC / 2)) * 2;
        bf16x2 z = {(__bf16)0.0f, (__bf16)0.0f};
        *(bf16x2*)&xp[0][r][cc] = z;
        *(bf16x2*)&xp[1][r][cc] = z;
        *(bf16x2*)&xp[2][r][cc] = z;
    }
    __syncthreads();

    const int wave = tid >> 6;
    const int lane = tid & 63;
    const int row  = lane & 15;
    const int hi   = lane >> 4;
    const int h0w  = wave * 64;
    const int PL   = XPR * XPC;                  // xp plane stride (elements)

    f32x4 acc[4][4];
#pragma unroll
    for (int m = 0; m < 4; m++)
#pragma unroll
        for (int n = 0; n < 4; n++)
#pragma unroll
            for (int r = 0; r < 4; r++) acc[m][n][r] = 0.0f;

    // swizzled B base for (ks, nf): wtb + ((wave*4+nf)*8 + ks)*512 + lane*8
    const __bf16* bw = wtb + ((size_t)wave * 4 * 8) * 512 + (size_t)lane * 8;

    // B prefetch: group g (0..31): ks=g>>2, nf=g&3, slot=g&3. 4-deep rotation.
    bf16x8 bb[4][3];
#pragma unroll
    for (int g = 0; g < 4; g++) {
        const __bf16* bp = bw + ((size_t)(g & 3) * 8 + 0) * 512;   // ks=0
        bb[g][0] = *(const bf16x8*)bp;
        bb[g][1] = *(const bf16x8*)(bp + BSWZ_PL);
        bb[g][2] = *(const bf16x8*)(bp + 2 * BSWZ_PL);
    }

    bf16x8 a[2][4][3];                            // double-buffered A
    {   // A for ks=0
        const int kb0 = hi * 8;
        const int dk = (kb0 >= 160) ? 2 : ((kb0 >= 80) ? 1 : 0);
        const int ci0 = kb0 - dk * 80;
#pragma unroll
        for (int m = 0; m < 4; m++) {
            const __bf16* ap = &xp[0][row + m * 16 + dk][ci0];
            a[0][m][0] = *(const bf16x8*)ap;
            a[0][m][1] = *(const bf16x8*)(ap + PL);
            a[0][m][2] = *(const bf16x8*)(ap + 2 * PL);
        }
    }

#pragma unroll
    for (int g = 0; g < 32; g++) {
        const int ks = g >> 2, nf = g & 3, slot = g & 3, ab = ks & 1;

#pragma unroll
        for (int m = 0; m < 4; m++) {
            acc[m][nf] = __builtin_amdgcn_mfma_f32_16x16x32_bf16(a[ab][m][0], bb[slot][0], acc[m][nf], 0, 0, 0);
            acc[m][nf] = __builtin_amdgcn_mfma_f32_16x16x32_bf16(a[ab][m][0], bb[slot][1], acc[m][nf], 0, 0, 0);
            acc[m][nf] = __builtin_amdgcn_mfma_f32_16x16x32_bf16(a[ab][m][1], bb[slot][0], acc[m][nf], 0, 0, 0);
            acc[m][nf] = __builtin_amdgcn_mfma_f32_16x16x32_bf16(a[ab][m][0], bb[slot][2], acc[m][nf], 0, 0, 0);
            acc[m][nf] = __builtin_amdgcn_mfma_f32_16x16x32_bf16(a[ab][m][1], bb[slot][1], acc[m][nf], 0, 0, 0);
            acc[m][nf] = __builtin_amdgcn_mfma_f32_16x16x32_bf16(a[ab][m][2], bb[slot][0], acc[m][nf], 0, 0, 0);
        }

        // A prefetch for ks+1 at nf==2
        if (nf == 2 && ks + 1 < 8) {
            const int kb0 = (ks + 1) * 32 + hi * 8;
            const int dk = (kb0 >= 160) ? 2 : ((kb0 >= 80) ? 1 : 0);
            const int ci0 = kb0 - dk * 80;
            const bool pad = (kb0 >= KTOT);
#pragma unroll
            for (int m = 0; m < 4; m++) {
                const __bf16* ap = pad ? &xp[0][66][0] : &xp[0][row + m * 16 + dk][ci0];
                a[ab ^ 1][m][0] = *(const bf16x8*)ap;
                a[ab ^ 1][m][1] = *(const bf16x8*)(ap + PL);
                a[ab ^ 1][m][2] = *(const bf16x8*)(ap + 2 * PL);
            }
        }

        // B prefetch for group g+4 into the slot just consumed (coalesced 1 KB)
        if (g + 4 < 32) {
            const int g4 = g + 4;
            const __bf16* bp = bw + ((size_t)(g4 & 3) * 8 + (g4 >> 2)) * 512;
            bb[slot][0] = *(const bf16x8*)bp;
            bb[slot][1] = *(const bf16x8*)(bp + BSWZ_PL);
            bb[slot][2] = *(const bf16x8*)(bp + 2 * BSWZ_PL);
        }
    }

    // epilogue: bias + y stores + fused BN partials (C: col=row, row=4*hi+r)
    const int blk = b * NTB + tb;
#pragma unroll
    for (int nf = 0; nf < 4; nf++) {
        const int h_out = h0w + nf * 16 + row;
        const double bv = ld_in(bias, h_out, isbf);
        double s1 = 0.0, s2 = 0.0;
#pragma unroll
        for (int m = 0; m < 4; m++)
#pragma unroll
            for (int r = 0; r < 4; r++) {
                double v = (double)acc[m][nf][r] + bv;
                y[((size_t)(t0 + m * 16 + 4 * hi + r) * B_DIM + b) * H_DIM + h_out] = (float)v;
                s1 += v;
                s2 = fma(v, v, s2);
            }
        s1 += __shfl_xor(s1, 16); s1 += __shfl_xor(s1, 32);
        s2 += __shfl_xor(s2, 16); s2 += __shfl_xor(s2, 32);
        if (hi == 0) {
            ps[(size_t)blk * H_DIM + h0w + nf * 16 + row] = s1;
            pq[(size_t)blk * H_DIM + h0w + nf * 16 + row] = s2;
        }
    }
}

// ---- kernel 1F: f32 VALU conv fallback (runs only if probe failed) ----
__global__ __launch_bounds__(256, 8) void k_convf(const void* __restrict__ x,
                                                  const void* __restrict__ bias,
                                                  const int* __restrict__ flag,
                                                  const float* __restrict__ wtf,
                                                  float* __restrict__ y,
                                                  double* __restrict__ ps,
                                                  double* __restrict__ pq) {
    if (flag[1] == 1) return;
    __shared__ __align__(16) float xs[CIN * (TT + 2)];
    const int isbf = flag[0];
    const int tb = blockIdx.x;
    const int b  = blockIdx.y;
    const int t0 = tb * TT;

    for (int idx = threadIdx.x; idx < CIN * (TT + 2); idx += 256) {
        int tl = idx / CIN;
        int ci = idx - tl * CIN;
        int tg = t0 - 1 + tl;
        float v = 0.0f;
        if (tg >= 0 && tg < T_DIM) v = ldf(x, (b * T_DIM + tg) * CIN + ci, isbf);
        xs[ci * (TT + 2) + tl] = v;
    }
    __syncthreads();

    const int h = threadIdx.x;
    float acc[TT];
    const float bv = ldf(bias, h, isbf);
#pragma unroll
    for (int i = 0; i < TT; i++) acc[i] = bv;

    const float* wp = wtf + h;
    float w0 = wp[0], w1 = wp[H_DIM], w2 = wp[2 * H_DIM];
    for (int ci = 0; ci < CIN; ci++) {
        float wn0 = 0.0f, wn1 = 0.0f, wn2 = 0.0f;
        if (ci + 1 < CIN) {
            const float* wq = wtf + (size_t)(ci + 1) * 3 * H_DIM + h;
            wn0 = wq[0]; wn1 = wq[H_DIM]; wn2 = wq[2 * H_DIM];
        }
        const float* xr = xs + ci * (TT + 2);
        float x0 = xr[0], x1 = xr[1];
#pragma unroll
        for (int tt = 0; tt < TT; tt += 2) {
            float2 xp2 = *(const float2*)(xr + tt + 2);
            acc[tt]     = fmaf(w2, xp2.x, fmaf(w1, x1,    fmaf(w0, x0, acc[tt])));
            acc[tt + 1] = fmaf(w2, xp2.y, fmaf(w1, xp2.x, fmaf(w0, x1, acc[tt + 1])));
            x0 = xp2.x; x1 = xp2.y;
        }
        w0 = wn0; w1 = wn1; w2 = wn2;
    }

    const int blk = b * NTB + tb;
    double s1 = 0.0, s2 = 0.0;
#pragma unroll
    for (int tt = 0; tt < TT; tt++) {
        y[((size_t)(t0 + tt) * B_DIM + b) * H_DIM + h] = acc[tt];
        double a = (double)acc[tt];
        s1 += a;
        s2 = fma(a, a, s2);
    }
    ps[(size_t)blk * H_DIM + h] = s1;
    pq[(size_t)blk * H_DIM + h] = s2;
}

// ---- kernel 2a: partial BN reduce ----
__global__ __launch_bounds__(256) void k_statsA(const double* __restrict__ ps,
                                                const double* __restrict__ pq,
                                                double* __restrict__ pa,
                                                double* __restrict__ pb) {
    const int h = threadIdx.x;
    const int k = blockIdx.x;
    double s1 = 0.0, s2 = 0.0;
    const int j0 = k * JPER;
    for (int j = j0; j < j0 + JPER; j++) {
        s1 += ps[(size_t)j * H_DIM + h];
        s2 += pq[(size_t)j * H_DIM + h];
    }
    pa[(size_t)k * H_DIM + h] = s1;
    pb[(size_t)k * H_DIM + h] = s2;
}

// ---- kernel 2b: final reduce + fold BN affine (once, in 1 block — R24 lesson) ----
__global__ __launch_bounds__(256) void k_statsB(const double* __restrict__ pa,
                                                const double* __restrict__ pb,
                                                const void* __restrict__ gamma,
                                                const void* __restrict__ beta,
                                                const int* __restrict__ flag,
                                                double* __restrict__ par) {
    const int isbf = flag[0];
    const int h = threadIdx.x;
    double s1 = 0.0, s2 = 0.0;
    for (int k = 0; k < NPART; k++) {
        s1 += pa[(size_t)k * H_DIM + h];
        s2 += pb[(size_t)k * H_DIM + h];
    }
    const double N = (double)T_DIM * (double)B_DIM;
    double mean = s1 / N;
    double var  = s2 / N - mean * mean;
    double r    = 1.0 / sqrt(var + 1e-5);
    par[h]       = mean;
    par[256 + h] = r * ld_in(gamma, h, isbf);
    par[512 + h] = ld_in(beta, h, isbf);
}

// ---- kernel 3: chunked LIF from f32 Y (no LDS, register double-buffer,
//      barrier-free). Flags margin-critical chains for f64 repair. ----
__global__ __launch_bounds__(256) void k_lif(const float* __restrict__ y,
                                             const double* __restrict__ par,
                                             const int* __restrict__ flag,
                                             unsigned char* __restrict__ flg,
                                             void* __restrict__ out) {
    const int isbf = flag[0];
    const int c = blockIdx.x, b = blockIdx.y, h = threadIdx.x;
    const int t_out = c * CLEN;
    int t_begin = t_out - WARM; if (t_begin < 0) t_begin = 0;
    const int nseg = (t_out + CLEN - t_begin) / SEG;   // 16 (c=0) or 22 — always even

    const double m  = par[h];
    const double A  = par[256 + h];
    const double be = par[512 + h];

    const size_t ST = (size_t)B_DIM * H_DIM;
    const float* yb = y + (size_t)b * H_DIM + h;
    u16*   ob16 = (u16*)out + (size_t)b * H_DIM + h;
    float* ob32 = (float*)out + (size_t)b * H_DIM + h;

    float ga[SEG], gb[SEG];
#pragma unroll
    for (int k = 0; k < SEG; k++) ga[k] = yb[(size_t)(t_begin + k) * ST];

    double v = 0.0;
    bool anyf = false;

#define LIF_SEG(GR, TBASE)                                                    \
    {                                                                         \
        const int t0s = (TBASE);                                              \
        _Pragma("unroll")                                                     \
        for (int k = 0; k < SEG; k++) {                                       \
            double val = fma((double)GR[k] - m, A, be);                       \
            v = fma(v, 0.5, val);                                             \
            double mg = v - 1.0;                                              \
            bool sp = mg >= 0.0;                                              \
            anyf |= (fabs(mg) < DELTA);                                       \
            const int t = t0s + k;                                            \
            if (t >= t_out) {                                                 \
                size_t oi = (size_t)t * ST;                                   \
                if (isbf) ob16[oi] = sp ? (u16)0x3F80 : (u16)0;               \
                else      ob32[oi] = sp ? 1.0f : 0.0f;                        \
            }                                                                 \
            v = sp ? 0.0 : v;                                                 \
        }                                                                     \
    }

    for (int s = 0; s < nseg; s += 2) {
        const int t1 = t_begin + (s + 1) * SEG;
        if (s + 1 < nseg) {
#pragma unroll
            for (int k = 0; k < SEG; k++) gb[k] = yb[(size_t)(t1 + k) * ST];
        }
        LIF_SEG(ga, t_begin + s * SEG);
        const int t2 = t_begin + (s + 2) * SEG;
        if (s + 2 < nseg) {
#pragma unroll
            for (int k = 0; k < SEG; k++) ga[k] = yb[(size_t)(t2 + k) * ST];
        }
        if (s + 1 < nseg) LIF_SEG(gb, t1);
    }
#undef LIF_SEG

    if (anyf) flg[(b << 8) | h] = 1;
}

// ---- kernel 4: tiled f64 repair (validated R19). Grid (RCH, B); early-exit
//      if no flagged h; x staged once coalesced; thread ti computes t in
//      [7ti,7ti+7); per-h chunked LIF with WARM=48 resync (t<0 -> vs=0). ----
__global__ __launch_bounds__(256) void k_repair(const void* __restrict__ x,
                                                const void* __restrict__ bias,
                                                const double* __restrict__ wt,
                                                const double* __restrict__ par,
                                                const int* __restrict__ flag,
                                                const unsigned char* __restrict__ flg,
                                                void* __restrict__ out) {
    __shared__ int nf_s;
    __shared__ u16 hl[256];
    __shared__ float xs[CIN * (RNT + 2)];    // 36.5 KB
    __shared__ double vs[RNH * VSTR];        // 14.5 KB

    const int b = blockIdx.y;
    const int tid = threadIdx.x;

    if (tid == 0) nf_s = 0;
    __syncthreads();
    if (flg[(b << 8) | tid]) { int p = atomicAdd(&nf_s, 1); hl[p] = (u16)tid; }
    __syncthreads();
    const int nf = nf_s;
    if (nf == 0) return;

    const int isbf = flag[0];
    const int t_out = blockIdx.x * RCLEN;
    const int t_begin = t_out - WARM;

    for (int idx = tid; idx < CIN * (RNT + 2); idx += 256) {
        int tl = idx / CIN;
        int ci = idx - tl * CIN;
        int tg = t_begin - 1 + tl;
        float v = 0.0f;
        if (tg >= 0 && tg < T_DIM) v = ldf(x, (b * T_DIM + tg) * CIN + ci, isbf);
        xs[ci * (RNT + 2) + tl] = v;
    }

    const int hi = tid >> 4;                 // wave-aligned h-groups
    const int ti = tid & 15;                 // covers t = 7*ti .. 7*ti+6

    for (int g0 = 0; g0 < nf; g0 += RNH) {
        const int h = (g0 + hi < nf) ? (int)hl[g0 + hi] : -1;
        __syncthreads();

        if (h >= 0) {
            const double bv = ld_in(bias, h, isbf);
            const double m  = par[h];
            const double A  = par[256 + h];
            const double be = par[512 + h];
            double acc[7];
#pragma unroll
            for (int k = 0; k < 7; k++) acc[k] = bv;
            const double* wq = wt + h;
            for (int ci = 0; ci < CIN; ci++) {
                const double w0 = wq[0], w1 = wq[H_DIM], w2 = wq[2 * H_DIM];
                wq += 3 * H_DIM;
                const float* xr = xs + ci * (RNT + 2) + ti * 7;
                float xv[9];
#pragma unroll
                for (int j = 0; j < 9; j++) xv[j] = xr[j];
#pragma unroll
                for (int k = 0; k < 7; k++)
                    acc[k] = fma(w0, (double)xv[k],
                             fma(w1, (double)xv[k + 1],
                             fma(w2, (double)xv[k + 2], acc[k])));
            }
#pragma unroll
            for (int k = 0; k < 7; k++) {
                const int tt = ti * 7 + k;
                vs[hi * VSTR + tt] = (t_begin + tt < 0) ? 0.0 : fma(acc[k] - m, A, be);
            }
        }
        __syncthreads();

        if (tid < RNH && g0 + tid < nf) {
            const int h2 = (int)hl[g0 + tid];
            const double* vr = vs + tid * VSTR;
            double v = 0.0;
            for (int tt = 0; tt < RNT; tt++) {
                v = fma(v, 0.5, vr[tt]);
                bool sp = (v - 1.0) >= 0.0;
                const int t = t_begin + tt;
                if (t >= t_out) {
                    size_t oi = ((size_t)t * B_DIM + b) * H_DIM + h2;
                    if (isbf) ((u16*)out)[oi] = sp ? (u16)0x3F80 : (u16)0;
                    else      ((float*)out)[oi] = sp ? 1.0f : 0.0f;
                }
                v = sp ? 0.0 : v;
            }
        }
    }
}

// ---- diagnostic: ws too small ----
__global__ void k_code(u16* out, float code) {
    if (threadIdx.x == 0 && blockIdx.x == 0) {
        union { unsigned int i; float f; } cv; cv.f = code;
        out[0] = (u16)(cv.i >> 16);
    }
}

extern "C" void kernel_launch(void* const* d_in, const int* in_sizes, int n_in,
                              void* d_out, int out_size, void* d_ws, size_t ws_size,
                              hipStream_t stream) {
    const void* x     = d_in[0];
    const void* w     = d_in[1];
    const void* cb    = d_in[2];
    const void* gamma = d_in[3];
    const void* beta  = d_in[4];

    char* wsb   = (char*)d_ws;
    int* flag   = (int*)wsb;
    double* PS  = (double*)(wsb + PS_OFF);
    double* PQ  = (double*)(wsb + PQ_OFF);
    double* PAR = (double*)(wsb + PAR_OFF);
    double* WT  = (double*)(wsb + WT_OFF);
    float*  WTF = (float*)(wsb + WTF_OFF);
    double* PA  = (double*)(wsb + PA_OFF);
    double* PB  = (double*)(wsb + PB_OFF);
    unsigned char* FLG = (unsigned char*)(wsb + FLG_OFF);
    __bf16* WTB = (__bf16*)(wsb + WTB_OFF);
    float* Yp   = (float*)(wsb + Y_OFF);

    const size_t need = Y_OFF + Y_ELEMS * 4;

    if (ws_size < need) {
        hipMemsetAsync(d_out, 0, (size_t)out_size * 2, stream);
        k_code<<<1, 64, 0, stream>>>((u16*)d_out, 1000.0f);
        return;
    }

    k_prep<<<dim3(241), dim3(256), 0, stream>>>((const u16*)x, w, flag, WT, WTF, WTB, FLG);
    k_convb<<<dim3(NTB, B_DIM), dim3(256), 0, stream>>>(
        x, cb, flag, WTB, Yp, PS, PQ);
    k_convf<<<dim3(NTB, B_DIM), dim3(256), 0, stream>>>(
        x, cb, flag, WTF, Yp, PS, PQ);
    k_statsA<<<dim3(NPART), dim3(256), 0, stream>>>(PS, PQ, PA, PB);
    k_statsB<<<dim3(1), dim3(256), 0, stream>>>(PA, PB, gamma, beta, flag, PAR);
    k_lif<<<dim3(CHUNKS, B_DIM), dim3(256), 0, stream>>>(Yp, PAR, flag, FLG, d_out);
    k_repair<<<dim3(RCH, B_DIM), dim3(256), 0, stream>>>(
        x, cb, WT, PAR, flag, FLG, d_out);
}